// Round 6
// baseline (276.059 us; speedup 1.0000x reference)
//
#include <hip/hip_runtime.h>

// loss = a*sum(pn^2) + 2*sum(z)*sum(pn) + sum(z^2)*(N - a)
//   z = (margin - p) on positives, pn = p on negatives, a = #positives.
// Streaming reduction: 256 MiB read, one scalar out. Memory-latency-bound.
//
// R5 post-mortem: inline-asm load clause aborted at runtime -- VGPR-resident
// deep load batches are unwinnable from source (R3/R4: scheduler collapses
// them; R5: hand asm is RA-fragile). R6: get MLP without VGPRs via
// __builtin_amdgcn_global_load_lds (fire-and-forget DMA to LDS, HW-verified
// at width=16, m97). 8 x 1KB staged loads per wave, __syncthreads() drain,
// wave reads back its own LDS region. 32KB LDS/block -> 5 blocks/CU ->
// ~160KB in flight per CU (vs ~3KB in R2-R4).

constexpr float MARGIN = 1.0f;

#define BANK_STRIDE 32            // floats; 128 B = one L2 line per bank
#define BLOCK 256
#define WAVES 4                   // 256/64
#define SLOTS 4                   // 1KB staged loads per array per wave
#define GROUPS_PER_BLOCK (BLOCK * SLOTS)   // 1024 float4-groups per block

#define GLOBAL_AS __attribute__((address_space(1)))
#define LDS_AS    __attribute__((address_space(3)))

__device__ __forceinline__ float wave_reduce(float v) {
    #pragma unroll
    for (int off = 32; off > 0; off >>= 1) v += __shfl_down(v, off, 64);
    return v;
}

__global__ __launch_bounds__(BLOCK) void hinge2_reduce(
    const float* __restrict__ pred, const int* __restrict__ lab,
    float* __restrict__ ws, int nvec, int nbanks, int bank_stride)
{
    const float4* p4 = reinterpret_cast<const float4*>(pred);
    const int4*   l4 = reinterpret_cast<const int4*>(lab);

    __shared__ float4 sp_[WAVES][SLOTS][64];   // 16 KB
    __shared__ int4   sl_[WAVES][SLOTS][64];   // 16 KB

    float a = 0.f, sz = 0.f, sz2 = 0.f, sp = 0.f, sp2 = 0.f;

    #define ACC(px, lx) do {                         \
        float ispos = ((lx) == 1) ? 1.0f : 0.0f;     \
        float z  = ispos * (MARGIN - (px));          \
        a   += ispos;                                \
        sz  += z;                                    \
        sz2 += z * z;                                \
        float pn = ((lx) == 1) ? 0.0f : (px);        \
        sp  += pn;                                   \
        sp2 += pn * pn;                              \
    } while (0)
    #define ACC4(p, l) do {                          \
        ACC((p).x, (l).x); ACC((p).y, (l).y);        \
        ACC((p).z, (l).z); ACC((p).w, (l).w);        \
    } while (0)

    const int lane = threadIdx.x & 63;
    const int wid  = threadIdx.x >> 6;
    const int blockBase = blockIdx.x * GROUPS_PER_BLOCK;

    if (blockBase + GROUPS_PER_BLOCK <= nvec) {   // block-uniform condition
        // stage: 8 fire-and-forget 1KB DMA loads per wave, no live VGPRs.
        // LDS dest is wave-uniform base + lane*16 (m104) -- our layout is
        // exactly lane-contiguous per slot.
        #pragma unroll
        for (int s = 0; s < SLOTS; ++s) {
            int g = blockBase + wid * (SLOTS * 64) + s * 64 + lane;
            __builtin_amdgcn_global_load_lds(
                (const GLOBAL_AS void*)(p4 + g),
                (LDS_AS void*)&sp_[wid][s][0], 16, 0, 0);
        }
        #pragma unroll
        for (int s = 0; s < SLOTS; ++s) {
            int g = blockBase + wid * (SLOTS * 64) + s * 64 + lane;
            __builtin_amdgcn_global_load_lds(
                (const GLOBAL_AS void*)(l4 + g),
                (LDS_AS void*)&sl_[wid][s][0], 16, 0, 0);
        }
        __syncthreads();   // compiler emits s_waitcnt vmcnt(0) before barrier

        #pragma unroll
        for (int s = 0; s < SLOTS; ++s) {
            float4 p = sp_[wid][s][lane];
            int4   l = sl_[wid][s][lane];
            ACC4(p, l);
        }
    } else {
        // edge block: guarded plain loads (unused for N = 2^25)
        for (int s = 0; s < SLOTS; ++s) {
            int g = blockBase + wid * (SLOTS * 64) + s * 64 + lane;
            if (g < nvec) {
                float4 p = p4[g];
                int4   l = l4[g];
                ACC4(p, l);
            }
        }
    }
    #undef ACC4
    #undef ACC

    a   = wave_reduce(a);
    sz  = wave_reduce(sz);
    sz2 = wave_reduce(sz2);
    sp  = wave_reduce(sp);
    sp2 = wave_reduce(sp2);

    __shared__ float sdata[WAVES][5];
    if (lane == 0) {
        sdata[wid][0] = a;
        sdata[wid][1] = sz;
        sdata[wid][2] = sz2;
        sdata[wid][3] = sp;
        sdata[wid][4] = sp2;
    }
    __syncthreads();

    if (threadIdx.x == 0) {
        float t0 = 0.f, t1 = 0.f, t2 = 0.f, t3 = 0.f, t4 = 0.f;
        #pragma unroll
        for (int w = 0; w < WAVES; ++w) {
            t0 += sdata[w][0];
            t1 += sdata[w][1];
            t2 += sdata[w][2];
            t3 += sdata[w][3];
            t4 += sdata[w][4];
        }
        float* bank = ws + (blockIdx.x & (nbanks - 1)) * bank_stride;
        atomicAdd(&bank[0], t0);
        atomicAdd(&bank[1], t1);
        atomicAdd(&bank[2], t2);
        atomicAdd(&bank[3], t3);
        atomicAdd(&bank[4], t4);
    }
}

__global__ __launch_bounds__(256) void hinge2_final(
    const float* __restrict__ ws,
    const float* __restrict__ pred, const int* __restrict__ lab,
    float* __restrict__ out, int n, int tail_start,
    int nbanks, int bank_stride)
{
    int t = threadIdx.x;
    float a = 0.f, sz = 0.f, sz2 = 0.f, sp = 0.f, sp2 = 0.f;
    for (int b = t; b < nbanks; b += 256) {
        const float* bank = ws + b * bank_stride;
        a   += bank[0];
        sz  += bank[1];
        sz2 += bank[2];
        sp  += bank[3];
        sp2 += bank[4];
    }
    a   = wave_reduce(a);
    sz  = wave_reduce(sz);
    sz2 = wave_reduce(sz2);
    sp  = wave_reduce(sp);
    sp2 = wave_reduce(sp2);

    __shared__ float sdata[4][5];
    int lane = t & 63, wid = t >> 6;
    if (lane == 0) {
        sdata[wid][0] = a;  sdata[wid][1] = sz; sdata[wid][2] = sz2;
        sdata[wid][3] = sp; sdata[wid][4] = sp2;
    }
    __syncthreads();

    if (t == 0) {
        double A = 0, SZ = 0, SZ2 = 0, SP = 0, SP2 = 0;
        #pragma unroll
        for (int w = 0; w < 4; ++w) {
            A   += sdata[w][0];
            SZ  += sdata[w][1];
            SZ2 += sdata[w][2];
            SP  += sdata[w][3];
            SP2 += sdata[w][4];
        }
        for (int i = tail_start; i < n; ++i) {
            float p = pred[i];
            if (lab[i] == 1) {
                double z = (double)MARGIN - (double)p;
                A += 1.0; SZ += z; SZ2 += z * z;
            } else {
                SP += (double)p; SP2 += (double)p * (double)p;
            }
        }
        double loss = A * SP2 + 2.0 * SZ * SP + SZ2 * ((double)n - A);
        out[0] = (float)loss;
    }
}

extern "C" void kernel_launch(void* const* d_in, const int* in_sizes, int n_in,
                              void* d_out, int out_size, void* d_ws, size_t ws_size,
                              hipStream_t stream)
{
    const float* pred = (const float*)d_in[0];
    const int*   lab  = (const int*)d_in[1];
    float*       out  = (float*)d_out;
    float*       ws   = (float*)d_ws;

    int n    = in_sizes[0];
    int nvec = n >> 2;          // float4 / int4 groups
    int tail = nvec << 2;

    int bank_stride = BANK_STRIDE;
    size_t max_banks = ws_size / (bank_stride * sizeof(float));
    int nbanks = 1;
    if (max_banks == 0) { bank_stride = 5; nbanks = 1; }
    else { while (nbanks * 2 <= (int)max_banks && nbanks < 256) nbanks <<= 1; }

    // ws is re-poisoned to 0xAA before every timed launch — zero the banks
    hipMemsetAsync(ws, 0, (size_t)nbanks * bank_stride * sizeof(float), stream);

    int blocks = (nvec + GROUPS_PER_BLOCK - 1) / GROUPS_PER_BLOCK;  // 8192 for N=2^25
    if (blocks < 1) blocks = 1;
    hinge2_reduce<<<blocks, BLOCK, 0, stream>>>(pred, lab, ws, nvec, nbanks, bank_stride);
    hinge2_final<<<1, BLOCK, 0, stream>>>(ws, pred, lab, out, n, tail, nbanks, bank_stride);
}